// Round 1
// baseline (301.500 us; speedup 1.0000x reference)
//
#include <hip/hip_runtime.h>
#include <hip/hip_bf16.h>

// Problem constants (fixed by setup_inputs in the reference)
#define BB 64
#define TT 262144
#define CC 3
#define KK 16384        // power of two: tid>>14 = batch
#define HH 32
#define WIN 2

__global__ __launch_bounds__(256) void refiner_kernel(
    const float* __restrict__ x,        // [B,T,C]
    const int*   __restrict__ ids,      // [B,K]
    const float* __restrict__ W1,       // [C,H]
    const float* __restrict__ b1,       // [H]
    const float* __restrict__ W2,       // [H,1]
    const float* __restrict__ b2,       // [1]
    float*       __restrict__ out)      // [B,K]
{
    // Stage the tiny MLP weights in LDS (broadcast reads are bank-conflict free)
    __shared__ float sW1[CC * HH];
    __shared__ float sb1[HH];
    __shared__ float sW2[HH];
    __shared__ float sb2;

    const int t = threadIdx.x;
    if (t < CC * HH) sW1[t] = W1[t];
    if (t < HH) { sb1[t] = b1[t]; sW2[t] = W2[t]; }
    if (t == 0) sb2 = b2[0];
    __syncthreads();

    const int tid = blockIdx.x * blockDim.x + t;
    if (tid >= BB * KK) return;

    const int b   = tid >> 14;          // tid / K
    const int idx = ids[tid];

    const float* __restrict__ xb = x + (size_t)b * (size_t)TT * CC;

    // 5-point masked-mean window over rows [idx-2, idx+2]
    float s0 = 0.0f, s1 = 0.0f, s2 = 0.0f, cnt = 0.0f;
#pragma unroll
    for (int o = -WIN; o <= WIN; ++o) {
        const int pos = idx + o;
        if (pos >= 0 && pos < TT) {
            const float* __restrict__ p = xb + (size_t)pos * CC;
            s0 += p[0];
            s1 += p[1];
            s2 += p[2];
            cnt += 1.0f;
        }
    }
    const float p0 = s0 / cnt;
    const float p1 = s1 / cnt;
    const float p2 = s2 / cnt;

    // MLP: relu(pooled @ W1 + b1) @ W2 + b2
    float acc = sb2;
#pragma unroll
    for (int j = 0; j < HH; ++j) {
        float h = fmaf(p0, sW1[j],
                  fmaf(p1, sW1[HH + j],
                  fmaf(p2, sW1[2 * HH + j], sb1[j])));
        h = h > 0.0f ? h : 0.0f;
        acc = fmaf(h, sW2[j], acc);
    }

    out[tid] = acc;
}

extern "C" void kernel_launch(void* const* d_in, const int* in_sizes, int n_in,
                              void* d_out, int out_size, void* d_ws, size_t ws_size,
                              hipStream_t stream) {
    const float* x   = (const float*)d_in[0];
    const int*   ids = (const int*)  d_in[1];
    const float* W1  = (const float*)d_in[2];
    const float* b1  = (const float*)d_in[3];
    const float* W2  = (const float*)d_in[4];
    const float* b2  = (const float*)d_in[5];
    float* out = (float*)d_out;

    const int n = BB * KK;              // 1,048,576 outputs
    const int block = 256;
    const int grid = (n + block - 1) / block;
    refiner_kernel<<<grid, block, 0, stream>>>(x, ids, W1, b1, W2, b2, out);
}

// Round 2
// 268.034 us; speedup vs baseline: 1.1249x; 1.1249x over previous
//
#include <hip/hip_runtime.h>
#include <hip/hip_bf16.h>

// Problem constants (fixed by setup_inputs in the reference)
#define BB 64
#define TT 262144
#define CC 3
#define KK 16384        // power of two
#define HH 32
#define WIN 2

// 16B vector with only 4B alignment requirement: window base is 12B-strided,
// i.e. 4B-aligned. gfx950 global_load_dwordx4 supports dword alignment.
typedef float f32x4 __attribute__((ext_vector_type(4), aligned(4)));

__global__ __launch_bounds__(256) void refiner_kernel(
    const float* __restrict__ x,        // [B,T,C]
    const int*   __restrict__ ids,      // [B,K]
    const float* __restrict__ W1,       // [C,H]
    const float* __restrict__ b1,       // [H]
    const float* __restrict__ W2,       // [H,1]
    const float* __restrict__ b2,       // [1]
    float*       __restrict__ out)      // [B,K]
{
    // Tiny MLP weights in LDS (broadcast reads, conflict-free)
    __shared__ float sW1[CC * HH];
    __shared__ float sb1[HH];
    __shared__ float sW2[HH];
    __shared__ float sb2;

    const int t = threadIdx.x;
    if (t < CC * HH) sW1[t] = W1[t];
    if (t < HH) { sb1[t] = b1[t]; sW2[t] = W2[t]; }
    if (t == 0) sb2 = b2[0];
    __syncthreads();

    // XCD-locality swizzle: grid = 4096 blocks, dispatch round-robins XCDs by
    // blockIdx%8. Keep all 64 blocks of a batch on ONE XCD so its 3MB slab
    // stays in that XCD's 4MB L2. bijective mapping blockIdx -> (batch,chunk).
    const int bid   = blockIdx.x;
    const int xcd   = bid & 7;
    const int slot  = bid >> 3;          // [0,512)
    const int batch = ((slot >> 6) << 3) + xcd;   // [0,64)
    const int chunk = slot & 63;         // [0,64)
    const int tid   = batch * KK + chunk * 256 + t;

    const int idx = ids[tid];
    const float* __restrict__ xb = x + (size_t)batch * (size_t)TT * CC;

    float p0, p1, p2;
    if (idx >= WIN && idx < TT - WIN) {
        // Interior (99.998% of indices): 60 contiguous bytes, 4 overlapping
        // dwordx4 loads at dword offsets 0,4,8,11 -> dwords 0..14.
        const float* base = xb + (size_t)(idx - WIN) * CC;
        const f32x4 a = *(const f32x4*)(base);       // d0..3
        const f32x4 b = *(const f32x4*)(base + 4);   // d4..7
        const f32x4 c = *(const f32x4*)(base + 8);   // d8..11
        const f32x4 d = *(const f32x4*)(base + 11);  // d11..14
        // rows: r0=d0..2 r1=d3..5 r2=d6..8 r3=d9..11 r4=d12..14
        const float s0 = a.x + a.w + b.z + c.y + d.y;   // channel 0
        const float s1 = a.y + b.x + b.w + c.z + d.z;   // channel 1
        const float s2 = a.z + b.y + c.x + c.w + d.w;   // channel 2
        p0 = s0 * 0.2f;
        p1 = s1 * 0.2f;
        p2 = s2 * 0.2f;
    } else {
        // Boundary: masked mean with clipping (rare; whole-wave divergence
        // probability ~0.15%)
        float s0 = 0.0f, s1 = 0.0f, s2 = 0.0f, cnt = 0.0f;
#pragma unroll
        for (int o = -WIN; o <= WIN; ++o) {
            const int pos = idx + o;
            if (pos >= 0 && pos < TT) {
                const float* p = xb + (size_t)pos * CC;
                s0 += p[0];
                s1 += p[1];
                s2 += p[2];
                cnt += 1.0f;
            }
        }
        const float rc = 1.0f / cnt;
        p0 = s0 * rc;
        p1 = s1 * rc;
        p2 = s2 * rc;
    }

    // MLP: relu(pooled @ W1 + b1) @ W2 + b2
    float acc = sb2;
#pragma unroll
    for (int j = 0; j < HH; ++j) {
        float h = fmaf(p0, sW1[j],
                  fmaf(p1, sW1[HH + j],
                  fmaf(p2, sW1[2 * HH + j], sb1[j])));
        h = h > 0.0f ? h : 0.0f;
        acc = fmaf(h, sW2[j], acc);
    }

    out[tid] = acc;
}

extern "C" void kernel_launch(void* const* d_in, const int* in_sizes, int n_in,
                              void* d_out, int out_size, void* d_ws, size_t ws_size,
                              hipStream_t stream) {
    const float* x   = (const float*)d_in[0];
    const int*   ids = (const int*)  d_in[1];
    const float* W1  = (const float*)d_in[2];
    const float* b1  = (const float*)d_in[3];
    const float* W2  = (const float*)d_in[4];
    const float* b2  = (const float*)d_in[5];
    float* out = (float*)d_out;

    const int n = BB * KK;              // 1,048,576 outputs
    const int block = 256;
    const int grid = n / block;         // 4096, exact
    refiner_kernel<<<grid, block, 0, stream>>>(x, ids, W1, b1, W2, b2, out);
}

// Round 3
// 267.381 us; speedup vs baseline: 1.1276x; 1.0024x over previous
//
#include <hip/hip_runtime.h>
#include <hip/hip_bf16.h>

// Problem constants (fixed by setup_inputs in the reference)
#define BB 64
#define TT 262144
#define CC 3
#define KK 16384        // power of two
#define HH 32
#define WIN 2

// 16B vector with only 4B alignment requirement: window base is 12B-strided,
// i.e. 4B-aligned. gfx950 global_load_dwordx4 supports dword alignment.
typedef float f32x4 __attribute__((ext_vector_type(4), aligned(4)));

__device__ __forceinline__ void pool_generic(const float* __restrict__ xb, int idx,
                                             float& p0, float& p1, float& p2) {
    float s0 = 0.f, s1 = 0.f, s2 = 0.f, cnt = 0.f;
#pragma unroll
    for (int o = -WIN; o <= WIN; ++o) {
        const int pos = idx + o;
        if (pos >= 0 && pos < TT) {
            const float* p = xb + (size_t)pos * CC;
            s0 += p[0]; s1 += p[1]; s2 += p[2]; cnt += 1.f;
        }
    }
    const float rc = 1.f / cnt;
    p0 = s0 * rc; p1 = s1 * rc; p2 = s2 * rc;
}

__global__ __launch_bounds__(256) void refiner_kernel(
    const float* __restrict__ x,        // [B,T,C]
    const int*   __restrict__ ids,      // [B,K]
    const float* __restrict__ W1,       // [C,H]  (uniform reads -> s_load)
    const float* __restrict__ b1,       // [H]
    const float* __restrict__ W2,       // [H]
    const float* __restrict__ b2,       // [1]
    float*       __restrict__ out)      // [B,K]
{
    const int t = threadIdx.x;

    // XCD-locality swizzle: 2048 blocks, dispatch round-robins XCDs by bid%8.
    // Keep each batch's 3MB slab resident in ONE XCD's 4MB L2.
    const int bid   = blockIdx.x;
    const int xcd   = bid & 7;
    const int slot  = bid >> 3;                    // [0,256)
    const int batch = ((slot >> 5) << 3) + xcd;    // [0,64)
    const int chunk = slot & 31;                   // [0,32)
    const int pair  = batch * KK + chunk * 512 + t * 2;  // even -> 8B aligned

    const int2 id2 = *(const int2*)(ids + pair);   // coalesced dwordx2
    const float* __restrict__ xb = x + (size_t)batch * (size_t)TT * CC;

    float a0, a1, a2, c0, c1, c2;                  // pooled channels, 2 outputs
    const int i0 = id2.x, i1 = id2.y;
    if (i0 >= WIN && i0 < TT - WIN && i1 >= WIN && i1 < TT - WIN) {
        // Interior fast path (~99.997% of thread pairs): two 60B windows,
        // 8 overlapping dwordx4 loads issued back-to-back (latency overlap).
        const float* ba = xb + (size_t)(i0 - WIN) * CC;
        const float* bb = xb + (size_t)(i1 - WIN) * CC;
        const f32x4 A0 = *(const f32x4*)(ba);       // d0..3
        const f32x4 A1 = *(const f32x4*)(ba + 4);   // d4..7
        const f32x4 A2 = *(const f32x4*)(ba + 8);   // d8..11
        const f32x4 A3 = *(const f32x4*)(ba + 11);  // d11..14
        const f32x4 B0 = *(const f32x4*)(bb);
        const f32x4 B1 = *(const f32x4*)(bb + 4);
        const f32x4 B2 = *(const f32x4*)(bb + 8);
        const f32x4 B3 = *(const f32x4*)(bb + 11);
        // rows: r0=d0..2 r1=d3..5 r2=d6..8 r3=d9..11 r4=d12..14
        a0 = (A0.x + A0.w + A1.z + A2.y + A3.y) * 0.2f;
        a1 = (A0.y + A1.x + A1.w + A2.z + A3.z) * 0.2f;
        a2 = (A0.z + A1.y + A2.x + A2.w + A3.w) * 0.2f;
        c0 = (B0.x + B0.w + B1.z + B2.y + B3.y) * 0.2f;
        c1 = (B0.y + B1.x + B1.w + B2.z + B3.z) * 0.2f;
        c2 = (B0.z + B1.y + B2.x + B2.w + B3.w) * 0.2f;
    } else {
        pool_generic(xb, i0, a0, a1, a2);
        pool_generic(xb, i1, c0, c1, c2);
    }

    // MLP for both outputs. Weight addresses are wave-uniform constants ->
    // compiler emits s_load through the scalar cache (parallel to VALU pipe);
    // each load serves BOTH outputs.
    float accA = b2[0];
    float accC = accA;
#pragma unroll
    for (int j = 0; j < HH; ++j) {
        const float w0 = W1[j];
        const float w1 = W1[HH + j];
        const float w2 = W1[2 * HH + j];
        const float bj = b1[j];
        const float vj = W2[j];
        float hA = fmaf(a0, w0, fmaf(a1, w1, fmaf(a2, w2, bj)));
        float hC = fmaf(c0, w0, fmaf(c1, w1, fmaf(c2, w2, bj)));
        hA = fmaxf(hA, 0.f);
        hC = fmaxf(hC, 0.f);
        accA = fmaf(hA, vj, accA);
        accC = fmaf(hC, vj, accC);
    }

    *(float2*)(out + pair) = make_float2(accA, accC);  // coalesced dwordx2
}

extern "C" void kernel_launch(void* const* d_in, const int* in_sizes, int n_in,
                              void* d_out, int out_size, void* d_ws, size_t ws_size,
                              hipStream_t stream) {
    const float* x   = (const float*)d_in[0];
    const int*   ids = (const int*)  d_in[1];
    const float* W1  = (const float*)d_in[2];
    const float* b1  = (const float*)d_in[3];
    const float* W2  = (const float*)d_in[4];
    const float* b2  = (const float*)d_in[5];
    float* out = (float*)d_out;

    const int n = BB * KK;              // 1,048,576 outputs, 2 per thread
    const int block = 256;
    const int grid = n / (block * 2);   // 2048, exact
    refiner_kernel<<<grid, block, 0, stream>>>(x, ids, W1, b1, W2, b2, out);
}